// Round 18
// baseline (845.999 us; speedup 1.0000x reference)
//
#include <hip/hip_runtime.h>
#include <hip/hip_cooperative_groups.h>
#include <stdint.h>

namespace cg = cooperative_groups;

#define N_NODES 100000
#define N_EDGES 1000000
#define IN_F 128
#define OUT_F 128
#define NUM_RELS 64
#define NB_SCAN ((N_NODES + 255) / 256)   // 391 chunks for the scan
#define N_WAVES 16384                     // gather wave-ranges
#define GATHER_B 256                      // persistent gather blocks (1/CU)
#define PREP_B 1024                       // coop prep blocks (4/CU, 256 thr)
#define GEMM_TILES ((N_NODES + 127) / 128) // 782
#define H16_ITEMS (N_NODES * IN_F / 8)    // 1.6M uint4s

typedef _Float16 half2v __attribute__((ext_vector_type(2)));

__device__ __forceinline__ float dot2f(uint32_t hu, uint32_t wu, float acc) {
#if __has_builtin(__builtin_amdgcn_fdot2)
    return __builtin_amdgcn_fdot2(__builtin_bit_cast(half2v, hu),
                                  __builtin_bit_cast(half2v, wu), acc, false);
#else
    half2v a = __builtin_bit_cast(half2v, hu);
    half2v b = __builtin_bit_cast(half2v, wu);
    acc = fmaf((float)a.x, (float)b.x, acc);
    acc = fmaf((float)a.y, (float)b.y, acc);
    return acc;
#endif
}

__device__ __forceinline__ uint32_t pkh2(float x, float y) {
    half2v v;
    v.x = (_Float16)x;    // RNE
    v.y = (_Float16)y;
    return __builtin_bit_cast(uint32_t, v);
}

// ---------------------------------------------------------------------------
// Shared device helpers
// ---------------------------------------------------------------------------
__device__ __forceinline__ void gemm_tile_body(
    const float* __restrict__ h, const float* __restrict__ W,
    const float* __restrict__ bias, float* __restrict__ out,
    int tile, int tid)
{
    const int ty = tid >> 4, tx = tid & 15;
    const int node0 = tile * 128 + ty * 8;
    const int o0 = tx * 8;

    float acc[8][8];
#pragma unroll
    for (int j = 0; j < 8; ++j)
#pragma unroll
        for (int i = 0; i < 8; ++i) acc[j][i] = 0.f;

    int nidx[8];
#pragma unroll
    for (int j = 0; j < 8; ++j) {
        int n = node0 + j;
        nidx[j] = n < N_NODES ? n : (N_NODES - 1);
    }

    for (int k = 0; k < IN_F; k += 4) {
        float hsv[8][4];
#pragma unroll
        for (int j = 0; j < 8; ++j) {
            float4 hv = *reinterpret_cast<const float4*>(h + (size_t)nidx[j] * IN_F + k);
            *reinterpret_cast<float4*>(hsv[j]) = hv;
        }
#pragma unroll
        for (int kk = 0; kk < 4; ++kk) {
            const float* wrow = W + (size_t)(k + kk) * OUT_F + o0;
            float wr[8];
            *reinterpret_cast<float4*>(wr)     = *reinterpret_cast<const float4*>(wrow);
            *reinterpret_cast<float4*>(wr + 4) = *reinterpret_cast<const float4*>(wrow + 4);
#pragma unroll
            for (int j = 0; j < 8; ++j) {
                const float hk = hsv[j][kk];
#pragma unroll
                for (int i = 0; i < 8; ++i)
                    acc[j][i] = fmaf(hk, wr[i], acc[j][i]);
            }
        }
    }

    float br[8];
    *reinterpret_cast<float4*>(br)     = *reinterpret_cast<const float4*>(bias + o0);
    *reinterpret_cast<float4*>(br + 4) = *reinterpret_cast<const float4*>(bias + o0 + 4);

#pragma unroll
    for (int j = 0; j < 8; ++j) {
        int n = node0 + j;
        if (n < N_NODES) {
            float4 v0, v1;
            v0.x = acc[j][0] + br[0]; v0.y = acc[j][1] + br[1];
            v0.z = acc[j][2] + br[2]; v0.w = acc[j][3] + br[3];
            v1.x = acc[j][4] + br[4]; v1.y = acc[j][5] + br[5];
            v1.z = acc[j][6] + br[6]; v1.w = acc[j][7] + br[7];
            float* op = out + (size_t)n * OUT_F + o0;
            *reinterpret_cast<float4*>(op)     = v0;
            *reinterpret_cast<float4*>(op + 4) = v1;
        }
    }
}

__device__ __forceinline__ void wsw_write_one(
    const float* __restrict__ weight, uint32_t* __restrict__ wsw, int t)
{
    int r    = t >> 9;
    int p    = t & 511;
    int half = p >> 8;
    int w8   = p & 255;
    int l    = w8 >> 2;
    int ip   = w8 & 3;
    int b    = l >> 2;
    int q    = l & 3;
    int o    = 2 * q + half;
    const float* s = weight + (size_t)r * 1024 + b * 64 + (2 * ip) * 8 + o;
    half2v v;
    v.x = (_Float16)s[0];
    v.y = (_Float16)s[8];
    wsw[t] = __builtin_bit_cast(uint32_t, v);
}

__device__ __forceinline__ void h16_write_one(
    const float* __restrict__ h, uint4* __restrict__ h16_4, int t2)
{
    const float4* hp = reinterpret_cast<const float4*>(h + (size_t)t2 * 8);
    float4 a = hp[0], c = hp[1];
    uint4 r;
    r.x = pkh2(a.x, a.y);
    r.y = pkh2(a.z, a.w);
    r.z = pkh2(c.x, c.y);
    r.w = pkh2(c.z, c.w);
    h16_4[t2] = r;
}

// ===========================================================================
// Cooperative PREP kernel (no big LDS -> high occupancy): all pre-gather
// phases with grid.sync between them. 1024 blocks x 256 threads (4/CU).
// ===========================================================================
__global__ __launch_bounds__(256, 4) void coop_prep(
    const float* __restrict__ h, const float* __restrict__ norm_,
    const float* __restrict__ weight, const float* __restrict__ loop_w,
    const float* __restrict__ bias, const int* __restrict__ src,
    const int* __restrict__ dst, const int* __restrict__ rel,
    float* __restrict__ out, int* __restrict__ cnt, int* __restrict__ off,
    int* __restrict__ cur, int* __restrict__ part, int* __restrict__ wstart,
    uint32_t* __restrict__ wsw, int2* __restrict__ emeta,
    uint4* __restrict__ h16_4)
{
    __shared__ int sdata[256];
    __shared__ int buf[256];

    cg::grid_group grid = cg::this_grid();

    const int tid  = threadIdx.x;
    const int gtid = blockIdx.x * 256 + tid;
    const int NT   = PREP_B * 256;              // 262144
    const int lane = tid & 63;

    // ---- P0: zero cnt + w-table + h16 + self-loop GEMM (independent) ----
    for (int i = gtid; i < N_NODES; i += NT) cnt[i] = 0;
    if (gtid < NUM_RELS * 512) wsw_write_one(weight, wsw, gtid);
    for (int t2 = gtid; t2 < H16_ITEMS; t2 += NT) h16_write_one(h, h16_4, t2);
    if (blockIdx.x < GEMM_TILES)
        gemm_tile_body(h, loop_w, bias, out, blockIdx.x, tid);
    grid.sync();

    // ---- P1: dst histogram ----
    for (int e = gtid; e < N_EDGES; e += NT)
        atomicAdd(&cnt[dst[e]], 1);
    grid.sync();

    // ---- P2: per-256-chunk sums (one wave per chunk) ----
    {
        int gw = gtid >> 6;
        if (gw < NB_SCAN) {
            int s = 0;
#pragma unroll
            for (int k = 0; k < 4; ++k) {
                int idx = gw * 256 + k * 64 + lane;
                s += (idx < N_NODES) ? cnt[idx] : 0;
            }
#pragma unroll
            for (int o = 32; o > 0; o >>= 1) s += __shfl_xor(s, o);
            if (lane == 0) part[gw] = s;
        }
    }
    grid.sync();

    // ---- P3: off[]/cur[] via per-block prefix over partials ----
    if (blockIdx.x < NB_SCAN) {
        const int bid = blockIdx.x;
        int psum = 0;
        for (int t = tid; t < bid; t += 256) psum += part[t];
        sdata[tid] = psum;
        __syncthreads();
        for (int s = 128; s > 0; s >>= 1) {
            if (tid < s) sdata[tid] += sdata[tid + s];
            __syncthreads();
        }
        const int blockoff = sdata[0];

        int i = bid * 256 + tid;
        int v = (i < N_NODES) ? cnt[i] : 0;
        buf[tid] = v;
        __syncthreads();
        for (int ofs = 1; ofs < 256; ofs <<= 1) {
            int t = (tid >= ofs) ? buf[tid - ofs] : 0;
            __syncthreads();
            buf[tid] += t;
            __syncthreads();
        }
        int excl = buf[tid] - v + blockoff;
        if (i < N_NODES) { off[i] = excl; cur[i] = excl; }
        if (i == N_NODES - 1) off[N_NODES] = N_EDGES;
    }
    grid.sync();

    // ---- P4: fill CSR + balanced wave partition + emeta pads ----
    for (int e = gtid; e < N_EDGES; e += NT) {
        int d = dst[e];
        int p = atomicAdd(&cur[d], 1);
        int2 m;
        m.x = src[e] | (rel[e] << 20);
        m.y = __float_as_int(norm_[e]);
        emeta[p] = m;
    }
    for (int w = gtid; w <= N_WAVES; w += NT) {
        if (w == 0) {
            wstart[0] = 0;
        } else if (w == N_WAVES) {
            wstart[N_WAVES] = N_NODES;
        } else {
            int target = (int)(((long long)N_EDGES * w) / N_WAVES);
            int lo = 0, hi = N_NODES - 1;
            while (lo < hi) {
                int mid = (lo + hi) >> 1;
                if (off[mid + 1] > target) hi = mid; else lo = mid + 1;
            }
            wstart[w] = lo;
        }
    }
    if (gtid < 3) { int2 z; z.x = 0; z.y = 0; emeta[N_EDGES + gtid] = z; }
}

// ===========================================================================
// Gather kernel (proven v10): fp16 table in LDS, persistent 256 blocks.
// ===========================================================================
__global__ __launch_bounds__(1024, 4) void gather_nodes10(
    const uint4* __restrict__ h16_4, const uint32_t* __restrict__ wsw,
    const int* __restrict__ off, const int2* __restrict__ emeta,
    const int* __restrict__ wstart, float* __restrict__ out)
{
    __shared__ uint32_t wlds[NUM_RELS * 512];   // 128 KB
    {
        uint4* l4 = reinterpret_cast<uint4*>(wlds);
        const uint4* g4 = reinterpret_cast<const uint4*>(wsw);
        int t = threadIdx.x;
#pragma unroll
        for (int k = 0; k < 8; ++k)
            l4[t + k * 1024] = g4[t + k * 1024];
    }
    __syncthreads();

    const int lane = threadIdx.x & 63;
    const int wid  = threadIdx.x >> 6;
    const int b = lane >> 2;
    const int q = lane & 3;
    const uint32_t lbase = (uint32_t)(lane * 4);

    for (int wv = blockIdx.x * 16 + wid; wv < N_WAVES; wv += GATHER_B * 16) {
        const int n0 = wstart[wv];
        const int n1 = wstart[wv + 1];
        if (n0 >= n1) continue;

        int j = off[n0];
        int e_next = off[n0 + 1];

        int2 m0 = emeta[j];
        int2 m1 = emeta[j + 1];
        int2 m2 = emeta[j + 2];
        uint4 hv0 = h16_4[((uint32_t)m0.x & 0xFFFFFu) * 16 + b];
        uint4 hv1 = h16_4[((uint32_t)m1.x & 0xFFFFFu) * 16 + b];

        uint32_t base0 = ((uint32_t)m0.x >> 20) * 512 + lbase;
        uint4 wa = *reinterpret_cast<const uint4*>(&wlds[base0]);
        uint4 wb = *reinterpret_cast<const uint4*>(&wlds[base0 + 256]);

        for (int d = n0; d < n1; ++d) {
            const int idx2 = (d + 2 < n1) ? d + 2 : n1;
            const int e_nn = off[idx2];
            float a0 = 0.f, a1 = 0.f;

            while (j < e_next) {
                int2 m3 = emeta[j + 3];
                uint4 hv2 = h16_4[((uint32_t)m2.x & 0xFFFFFu) * 16 + b];
                uint32_t bn = ((uint32_t)m1.x >> 20) * 512 + lbase;
                uint4 wna = *reinterpret_cast<const uint4*>(&wlds[bn]);
                uint4 wnb = *reinterpret_cast<const uint4*>(&wlds[bn + 256]);

                float s0 = dot2f(hv0.x, wa.x, 0.f);
                s0 = dot2f(hv0.y, wa.y, s0);
                s0 = dot2f(hv0.z, wa.z, s0);
                s0 = dot2f(hv0.w, wa.w, s0);
                float s1 = dot2f(hv0.x, wb.x, 0.f);
                s1 = dot2f(hv0.y, wb.y, s1);
                s1 = dot2f(hv0.z, wb.z, s1);
                s1 = dot2f(hv0.w, wb.w, s1);

                const float nm = __int_as_float(m0.y);
                a0 = fmaf(s0, nm, a0);
                a1 = fmaf(s1, nm, a1);

                m0 = m1; m1 = m2; m2 = m3;
                hv0 = hv1; hv1 = hv2;
                wa = wna; wb = wnb;
                ++j;
            }

            float2* op = reinterpret_cast<float2*>(out + (size_t)d * OUT_F + b * 8 + 2 * q);
            float2 bse = *op;
            float2 res;
            res.x = fmaxf(bse.x + a0, 0.f);
            res.y = fmaxf(bse.y + a1, 0.f);
            *op = res;

            e_next = e_nn;
        }
    }
}

// ===========================================================================
// Fallback path = proven R15 chain (fused prep+gemm, 309.5 us total).
// ===========================================================================
#define GEMM_B GEMM_TILES

__global__ __launch_bounds__(256) void prep_gemm_fused(
    const float* __restrict__ h, const float* __restrict__ W,
    const float* __restrict__ bias, float* __restrict__ out,
    const float* __restrict__ weight, uint32_t* __restrict__ wsw,
    const int* __restrict__ dst, int* __restrict__ cnt,
    uint4* __restrict__ h16_4, int n_edges, int do_h16)
{
    if (blockIdx.x < GEMM_B) {
        gemm_tile_body(h, W, bias, out, blockIdx.x, threadIdx.x);
        return;
    }
    int t = (blockIdx.x - GEMM_B) * 256 + threadIdx.x;
    if (t < NUM_RELS * 512) {
        wsw_write_one(weight, wsw, t);
        return;
    }
    int e = t - NUM_RELS * 512;
    if (e < n_edges) {
        atomicAdd(&cnt[dst[e]], 1);
        return;
    }
    if (!do_h16) return;
    int t2 = e - n_edges;
    if (t2 < H16_ITEMS) h16_write_one(h, h16_4, t2);
}

__global__ __launch_bounds__(256) void block_sums(
    const int* __restrict__ cnt, int* __restrict__ part, int n)
{
    __shared__ int sdata[256];
    int i = blockIdx.x * 256 + threadIdx.x;
    sdata[threadIdx.x] = (i < n) ? cnt[i] : 0;
    __syncthreads();
    for (int s = 128; s > 0; s >>= 1) {
        if (threadIdx.x < s) sdata[threadIdx.x] += sdata[threadIdx.x + s];
        __syncthreads();
    }
    if (threadIdx.x == 0) part[blockIdx.x] = sdata[0];
}

__global__ __launch_bounds__(256) void write_off2(
    const int* __restrict__ cnt, const int* __restrict__ part,
    int* __restrict__ off, int* __restrict__ cur, int n, int n_edges)
{
    __shared__ int sdata[256];
    __shared__ int buf[256];
    const int tid = threadIdx.x;
    const int bid = blockIdx.x;

    int psum = 0;
    for (int t = tid; t < bid; t += 256) psum += part[t];
    sdata[tid] = psum;
    __syncthreads();
    for (int s = 128; s > 0; s >>= 1) {
        if (tid < s) sdata[tid] += sdata[tid + s];
        __syncthreads();
    }
    const int blockoff = sdata[0];

    int i = bid * 256 + tid;
    int v = (i < n) ? cnt[i] : 0;
    buf[tid] = v;
    __syncthreads();
    for (int ofs = 1; ofs < 256; ofs <<= 1) {
        int t = (tid >= ofs) ? buf[tid - ofs] : 0;
        __syncthreads();
        buf[tid] += t;
        __syncthreads();
    }
    int excl = buf[tid] - v + blockoff;
    if (i < n) { off[i] = excl; cur[i] = excl; }
    if (i == n - 1) off[n] = n_edges;
}

__global__ __launch_bounds__(256) void fill_and_part(
    const int* __restrict__ src, const int* __restrict__ dst,
    const int* __restrict__ rel, const float* __restrict__ norm,
    int* __restrict__ cur, int2* __restrict__ emeta,
    const int* __restrict__ off, int* __restrict__ wstart, int n_edges)
{
    int t = blockIdx.x * 256 + threadIdx.x;
    if (t < n_edges) {
        int d = dst[t];
        int p = atomicAdd(&cur[d], 1);
        int2 m;
        m.x = src[t] | (rel[t] << 20);
        m.y = __float_as_int(norm[t]);
        emeta[p] = m;
    } else {
        int w = t - n_edges;
        if (w <= N_WAVES) {
            if (w == 0) {
                wstart[0] = 0;
            } else if (w == N_WAVES) {
                wstart[N_WAVES] = N_NODES;
            } else {
                int target = (int)(((long long)N_EDGES * w) / N_WAVES);
                int lo = 0, hi = N_NODES - 1;
                while (lo < hi) {
                    int mid = (lo + hi) >> 1;
                    if (off[mid + 1] > target) hi = mid; else lo = mid + 1;
                }
                wstart[w] = lo;
            }
        } else if (w <= N_WAVES + 3) {
            int2 z; z.x = 0; z.y = 0;
            emeta[n_edges + (w - N_WAVES - 1)] = z;
        }
    }
}

extern "C" void kernel_launch(void* const* d_in, const int* in_sizes, int n_in,
                              void* d_out, int out_size, void* d_ws, size_t ws_size,
                              hipStream_t stream)
{
    const float* h      = (const float*)d_in[0];
    const float* norm   = (const float*)d_in[1];
    const float* weight = (const float*)d_in[2];
    const float* loop_w = (const float*)d_in[3];
    const float* bias   = (const float*)d_in[4];
    const int*   src    = (const int*)d_in[5];
    const int*   dst    = (const int*)d_in[6];
    const int*   rel    = (const int*)d_in[7];
    float* out = (float*)d_out;

    // ws layout: cnt[N], off[N+1], cur[N], part[512], wstart[N_WAVES+1],
    // wsw[64*512 u32], emeta[E+3] int2, h16[N*IN_F] fp16  -> ~35 MB
    char* wsb = (char*)d_ws;
    char* ws0 = wsb;
    int*  cnt    = (int*)wsb;  wsb += sizeof(int) * N_NODES;
    int*  off    = (int*)wsb;  wsb += sizeof(int) * (N_NODES + 1);
    int*  cur    = (int*)wsb;  wsb += sizeof(int) * N_NODES;
    int*  part   = (int*)wsb;  wsb += sizeof(int) * 512;
    int*  wstart = (int*)wsb;  wsb += sizeof(int) * (N_WAVES + 1);
    wsb = (char*)(((uintptr_t)wsb + 15) & ~(uintptr_t)15);
    uint32_t* wsw = (uint32_t*)wsb; wsb += sizeof(uint32_t) * NUM_RELS * 512;
    int2* emeta = (int2*)wsb;  wsb += sizeof(int2) * (N_EDGES + 3);
    wsb = (char*)(((uintptr_t)wsb + 15) & ~(uintptr_t)15);
    uint4* h16_4 = (uint4*)wsb; wsb += (size_t)N_NODES * IN_F * 2;

    const int use_h16 = (size_t)(wsb - ws0) <= ws_size;   // host-constant

    if (use_h16) {
        void* args[] = {
            (void*)&h, (void*)&norm, (void*)&weight, (void*)&loop_w,
            (void*)&bias, (void*)&src, (void*)&dst, (void*)&rel,
            (void*)&out, (void*)&cnt, (void*)&off, (void*)&cur,
            (void*)&part, (void*)&wstart, (void*)&wsw, (void*)&emeta,
            (void*)&h16_4
        };
        hipError_t err = hipLaunchCooperativeKernel(
            (const void*)coop_prep, dim3(PREP_B), dim3(256), args, 0, stream);
        if (err == hipSuccess) {
            gather_nodes10<<<GATHER_B, 1024, 0, stream>>>(h16_4, wsw, off, emeta, wstart, out);
            return;
        }
        (void)hipGetLastError();   // clear error, fall through to legacy path
    }

    // --- legacy multi-launch path (R15, proven 309.5 us) ---
    hipMemsetAsync(cnt, 0, sizeof(int) * N_NODES, stream);
    const int h16_threads = use_h16 ? H16_ITEMS : 0;
    const int prep_blocks = (NUM_RELS * 512 + N_EDGES + h16_threads + 255) / 256;
    prep_gemm_fused<<<GEMM_B + prep_blocks, 256, 0, stream>>>(
        h, loop_w, bias, out, weight, wsw, dst, cnt, h16_4, N_EDGES, use_h16);
    block_sums<<<NB_SCAN, 256, 0, stream>>>(cnt, part, N_NODES);
    write_off2<<<NB_SCAN, 256, 0, stream>>>(cnt, part, off, cur, N_NODES, N_EDGES);
    const int fp_grid = (N_EDGES + N_WAVES + 4 + 255) / 256;
    fill_and_part<<<fp_grid, 256, 0, stream>>>(src, dst, rel, norm, cur, emeta,
                                               off, wstart, N_EDGES);
    gather_nodes10<<<GATHER_B, 1024, 0, stream>>>(h16_4, wsw, off, emeta, wstart, out);
}

// Round 19
// 320.525 us; speedup vs baseline: 2.6394x; 2.6394x over previous
//
#include <hip/hip_runtime.h>
#include <stdint.h>

#define N_NODES 100000
#define N_EDGES 1000000
#define IN_F 128
#define OUT_F 128
#define NUM_RELS 64
#define NB_SCAN ((N_NODES + 255) / 256)   // 391 blocks for the scan
#define N_WAVES 16384                     // gather wave-ranges
#define GATHER_B 256                      // persistent gather blocks (1/CU)
#define GEMM_TILES ((N_NODES + 127) / 128) // 782
#define H16_ITEMS (N_NODES * IN_F / 8)    // 1.6M uint4s

typedef _Float16 half2v __attribute__((ext_vector_type(2)));

__device__ __forceinline__ float dot2f(uint32_t hu, uint32_t wu, float acc) {
#if __has_builtin(__builtin_amdgcn_fdot2)
    return __builtin_amdgcn_fdot2(__builtin_bit_cast(half2v, hu),
                                  __builtin_bit_cast(half2v, wu), acc, false);
#else
    half2v a = __builtin_bit_cast(half2v, hu);
    half2v b = __builtin_bit_cast(half2v, wu);
    acc = fmaf((float)a.x, (float)b.x, acc);
    acc = fmaf((float)a.y, (float)b.y, acc);
    return acc;
#endif
}

__device__ __forceinline__ uint32_t pkh2(float x, float y) {
    half2v v;
    v.x = (_Float16)x;    // RNE
    v.y = (_Float16)y;
    return __builtin_bit_cast(uint32_t, v);
}

__device__ __forceinline__ void wsw_write_one(
    const float* __restrict__ weight, uint32_t* __restrict__ wsw, int t)
{
    int r    = t >> 9;
    int p    = t & 511;
    int half = p >> 8;
    int w8   = p & 255;
    int l    = w8 >> 2;
    int ip   = w8 & 3;
    int b    = l >> 2;
    int q    = l & 3;
    int o    = 2 * q + half;
    const float* s = weight + (size_t)r * 1024 + b * 64 + (2 * ip) * 8 + o;
    half2v v;
    v.x = (_Float16)s[0];
    v.y = (_Float16)s[8];
    wsw[t] = __builtin_bit_cast(uint32_t, v);
}

// ---------------------------------------------------------------------------
// Kernel A: self-loop GEMM + h16 side-product.
// Block = 128-node x 128-out tile (8x8 reg tile / thread). After the C-write,
// the block converts its 128 h rows to fp16 (rows are L2-hot: just read).
// ---------------------------------------------------------------------------
__global__ __launch_bounds__(256) void gemm_h16(
    const float* __restrict__ h, const float* __restrict__ W,
    const float* __restrict__ bias, float* __restrict__ out,
    uint4* __restrict__ h16_4, int do_h16)
{
    const int tid = threadIdx.x;
    const int ty = tid >> 4, tx = tid & 15;
    const int node0 = blockIdx.x * 128 + ty * 8;
    const int o0 = tx * 8;

    float acc[8][8];
#pragma unroll
    for (int j = 0; j < 8; ++j)
#pragma unroll
        for (int i = 0; i < 8; ++i) acc[j][i] = 0.f;

    int nidx[8];
#pragma unroll
    for (int j = 0; j < 8; ++j) {
        int n = node0 + j;
        nidx[j] = n < N_NODES ? n : (N_NODES - 1);
    }

    for (int k = 0; k < IN_F; k += 4) {
        float hsv[8][4];
#pragma unroll
        for (int j = 0; j < 8; ++j) {
            float4 hv = *reinterpret_cast<const float4*>(h + (size_t)nidx[j] * IN_F + k);
            *reinterpret_cast<float4*>(hsv[j]) = hv;
        }
#pragma unroll
        for (int kk = 0; kk < 4; ++kk) {
            const float* wrow = W + (size_t)(k + kk) * OUT_F + o0;
            float wr[8];
            *reinterpret_cast<float4*>(wr)     = *reinterpret_cast<const float4*>(wrow);
            *reinterpret_cast<float4*>(wr + 4) = *reinterpret_cast<const float4*>(wrow + 4);
#pragma unroll
            for (int j = 0; j < 8; ++j) {
                const float hk = hsv[j][kk];
#pragma unroll
                for (int i = 0; i < 8; ++i)
                    acc[j][i] = fmaf(hk, wr[i], acc[j][i]);
            }
        }
    }

    float br[8];
    *reinterpret_cast<float4*>(br)     = *reinterpret_cast<const float4*>(bias + o0);
    *reinterpret_cast<float4*>(br + 4) = *reinterpret_cast<const float4*>(bias + o0 + 4);

#pragma unroll
    for (int j = 0; j < 8; ++j) {
        int n = node0 + j;
        if (n < N_NODES) {
            float4 v0, v1;
            v0.x = acc[j][0] + br[0]; v0.y = acc[j][1] + br[1];
            v0.z = acc[j][2] + br[2]; v0.w = acc[j][3] + br[3];
            v1.x = acc[j][4] + br[4]; v1.y = acc[j][5] + br[5];
            v1.z = acc[j][6] + br[6]; v1.w = acc[j][7] + br[7];
            float* op = out + (size_t)n * OUT_F + o0;
            *reinterpret_cast<float4*>(op)     = v0;
            *reinterpret_cast<float4*>(op + 4) = v1;
        }
    }

    // ---- h16 side-product for this tile's nodes (rows L2-hot) ----
    if (do_h16) {
        int node = blockIdx.x * 128 + (tid >> 1);
        if (node < N_NODES) {
            const int c0 = (tid & 1) * 64;   // 64 floats = 8 uint4 outputs
            const float4* hp = reinterpret_cast<const float4*>(
                h + (size_t)node * IN_F + c0);
            uint4* dst4 = h16_4 + (size_t)node * 16 + (tid & 1) * 8;
#pragma unroll
            for (int k = 0; k < 8; ++k) {
                float4 a = hp[2 * k];
                float4 c = hp[2 * k + 1];
                uint4 r;
                r.x = pkh2(a.x, a.y);
                r.y = pkh2(a.z, a.w);
                r.z = pkh2(c.x, c.y);
                r.w = pkh2(c.z, c.w);
                dst4[k] = r;
            }
        }
    }
}

// ---------------------------------------------------------------------------
// hist + wsw table build (tiny, high-occupancy, latency-bound).
// ---------------------------------------------------------------------------
__global__ __launch_bounds__(256) void hist_wsw(
    const float* __restrict__ weight, uint32_t* __restrict__ wsw,
    const int* __restrict__ dst, int* __restrict__ cnt, int n_edges)
{
    int t = blockIdx.x * 256 + threadIdx.x;
    if (t < NUM_RELS * 512) {
        wsw_write_one(weight, wsw, t);
        return;
    }
    int e = t - NUM_RELS * 512;
    if (e < n_edges) atomicAdd(&cnt[dst[e]], 1);
}

__global__ __launch_bounds__(256) void block_sums(
    const int* __restrict__ cnt, int* __restrict__ part, int n)
{
    __shared__ int sdata[256];
    int i = blockIdx.x * 256 + threadIdx.x;
    sdata[threadIdx.x] = (i < n) ? cnt[i] : 0;
    __syncthreads();
    for (int s = 128; s > 0; s >>= 1) {
        if (threadIdx.x < s) sdata[threadIdx.x] += sdata[threadIdx.x + s];
        __syncthreads();
    }
    if (threadIdx.x == 0) part[blockIdx.x] = sdata[0];
}

__global__ __launch_bounds__(256) void write_off2(
    const int* __restrict__ cnt, const int* __restrict__ part,
    int* __restrict__ off, int* __restrict__ cur, int n, int n_edges)
{
    __shared__ int sdata[256];
    __shared__ int buf[256];
    const int tid = threadIdx.x;
    const int bid = blockIdx.x;

    int psum = 0;
    for (int t = tid; t < bid; t += 256) psum += part[t];
    sdata[tid] = psum;
    __syncthreads();
    for (int s = 128; s > 0; s >>= 1) {
        if (tid < s) sdata[tid] += sdata[tid + s];
        __syncthreads();
    }
    const int blockoff = sdata[0];

    int i = bid * 256 + tid;
    int v = (i < n) ? cnt[i] : 0;
    buf[tid] = v;
    __syncthreads();
    for (int ofs = 1; ofs < 256; ofs <<= 1) {
        int t = (tid >= ofs) ? buf[tid - ofs] : 0;
        __syncthreads();
        buf[tid] += t;
        __syncthreads();
    }
    int excl = buf[tid] - v + blockoff;
    if (i < n) { off[i] = excl; cur[i] = excl; }
    if (i == n - 1) off[n] = n_edges;
}

__global__ __launch_bounds__(256) void fill_and_part(
    const int* __restrict__ src, const int* __restrict__ dst,
    const int* __restrict__ rel, const float* __restrict__ norm,
    int* __restrict__ cur, int2* __restrict__ emeta,
    const int* __restrict__ off, int* __restrict__ wstart, int n_edges)
{
    int t = blockIdx.x * 256 + threadIdx.x;
    if (t < n_edges) {
        int d = dst[t];
        int p = atomicAdd(&cur[d], 1);
        int2 m;
        m.x = src[t] | (rel[t] << 20);
        m.y = __float_as_int(norm[t]);
        emeta[p] = m;
    } else {
        int w = t - n_edges;
        if (w <= N_WAVES) {
            if (w == 0) {
                wstart[0] = 0;
            } else if (w == N_WAVES) {
                wstart[N_WAVES] = N_NODES;
            } else {
                int target = (int)(((long long)N_EDGES * w) / N_WAVES);
                int lo = 0, hi = N_NODES - 1;
                while (lo < hi) {
                    int mid = (lo + hi) >> 1;
                    if (off[mid + 1] > target) hi = mid; else lo = mid + 1;
                }
                wstart[w] = lo;
            }
        } else if (w <= N_WAVES + 3) {
            int2 z; z.x = 0; z.y = 0;
            emeta[n_edges + (w - N_WAVES - 1)] = z;   // 3 zero pads
        }
    }
}

// ---------------------------------------------------------------------------
// Hot kernel v10 (proven): fp16 table in LDS, persistent 256 blocks.
// Per edge: 1 meta + 1 uint4 h16 load + 2 ds_read_b128 + 8 fdot2 + 2 fma.
// ---------------------------------------------------------------------------
__global__ __launch_bounds__(1024, 4) void gather_nodes10(
    const uint4* __restrict__ h16_4, const uint32_t* __restrict__ wsw,
    const int* __restrict__ off, const int2* __restrict__ emeta,
    const int* __restrict__ wstart, float* __restrict__ out)
{
    __shared__ uint32_t wlds[NUM_RELS * 512];   // 128 KB
    {
        uint4* l4 = reinterpret_cast<uint4*>(wlds);
        const uint4* g4 = reinterpret_cast<const uint4*>(wsw);
        int t = threadIdx.x;
#pragma unroll
        for (int k = 0; k < 8; ++k)
            l4[t + k * 1024] = g4[t + k * 1024];
    }
    __syncthreads();

    const int lane = threadIdx.x & 63;
    const int wid  = threadIdx.x >> 6;
    const int b = lane >> 2;
    const int q = lane & 3;
    const uint32_t lbase = (uint32_t)(lane * 4);

    for (int wv = blockIdx.x * 16 + wid; wv < N_WAVES; wv += GATHER_B * 16) {
        const int n0 = wstart[wv];
        const int n1 = wstart[wv + 1];
        if (n0 >= n1) continue;

        int j = off[n0];
        int e_next = off[n0 + 1];

        int2 m0 = emeta[j];
        int2 m1 = emeta[j + 1];
        int2 m2 = emeta[j + 2];
        uint4 hv0 = h16_4[((uint32_t)m0.x & 0xFFFFFu) * 16 + b];
        uint4 hv1 = h16_4[((uint32_t)m1.x & 0xFFFFFu) * 16 + b];

        uint32_t base0 = ((uint32_t)m0.x >> 20) * 512 + lbase;
        uint4 wa = *reinterpret_cast<const uint4*>(&wlds[base0]);
        uint4 wb = *reinterpret_cast<const uint4*>(&wlds[base0 + 256]);

        for (int d = n0; d < n1; ++d) {
            const int idx2 = (d + 2 < n1) ? d + 2 : n1;
            const int e_nn = off[idx2];
            float a0 = 0.f, a1 = 0.f;

            while (j < e_next) {
                int2 m3 = emeta[j + 3];
                uint4 hv2 = h16_4[((uint32_t)m2.x & 0xFFFFFu) * 16 + b];
                uint32_t bn = ((uint32_t)m1.x >> 20) * 512 + lbase;
                uint4 wna = *reinterpret_cast<const uint4*>(&wlds[bn]);
                uint4 wnb = *reinterpret_cast<const uint4*>(&wlds[bn + 256]);

                float s0 = dot2f(hv0.x, wa.x, 0.f);
                s0 = dot2f(hv0.y, wa.y, s0);
                s0 = dot2f(hv0.z, wa.z, s0);
                s0 = dot2f(hv0.w, wa.w, s0);
                float s1 = dot2f(hv0.x, wb.x, 0.f);
                s1 = dot2f(hv0.y, wb.y, s1);
                s1 = dot2f(hv0.z, wb.z, s1);
                s1 = dot2f(hv0.w, wb.w, s1);

                const float nm = __int_as_float(m0.y);
                a0 = fmaf(s0, nm, a0);
                a1 = fmaf(s1, nm, a1);

                m0 = m1; m1 = m2; m2 = m3;
                hv0 = hv1; hv1 = hv2;
                wa = wna; wb = wnb;
                ++j;
            }

            float2* op = reinterpret_cast<float2*>(out + (size_t)d * OUT_F + b * 8 + 2 * q);
            float2 bse = *op;
            float2 res;
            res.x = fmaxf(bse.x + a0, 0.f);
            res.y = fmaxf(bse.y + a1, 0.f);
            *op = res;

            e_next = e_nn;
        }
    }
}

// ---------------------------------------------------------------------------
// Fallback hot kernel (h in f32) if ws_size can't hold h16. Same w layout.
// ---------------------------------------------------------------------------
__global__ __launch_bounds__(1024, 4) void gather_nodes6(
    const float* __restrict__ h, const uint32_t* __restrict__ wsw,
    const int* __restrict__ off, const int2* __restrict__ emeta,
    const int* __restrict__ wstart, float* __restrict__ out)
{
    __shared__ uint32_t wlds[NUM_RELS * 512];   // 128 KB
    {
        uint4* l4 = reinterpret_cast<uint4*>(wlds);
        const uint4* g4 = reinterpret_cast<const uint4*>(wsw);
        int t = threadIdx.x;
#pragma unroll
        for (int k = 0; k < 8; ++k)
            l4[t + k * 1024] = g4[t + k * 1024];
    }
    __syncthreads();

    const int lane = threadIdx.x & 63;
    const int wid  = threadIdx.x >> 6;
    const int b = lane >> 2;
    const int q = lane & 3;
    const uint32_t lbase = (uint32_t)(lane * 4);

    for (int wv = blockIdx.x * 16 + wid; wv < N_WAVES; wv += GATHER_B * 16) {
        const int n0 = wstart[wv];
        const int n1 = wstart[wv + 1];
        if (n0 >= n1) continue;

        int j = off[n0];
        int2 m0 = emeta[j];
        int2 m1 = emeta[j + 1];
        int2 m2 = emeta[j + 2];

        const float4* hr0 = reinterpret_cast<const float4*>(
            h + (size_t)((uint32_t)m0.x & 0xFFFFFu) * IN_F + b * 8);
        float4 h0A = hr0[0], h0B = hr0[1];
        const float4* hr1 = reinterpret_cast<const float4*>(
            h + (size_t)((uint32_t)m1.x & 0xFFFFFu) * IN_F + b * 8);
        float4 h1A = hr1[0], h1B = hr1[1];

        uint32_t base0 = ((uint32_t)m0.x >> 20) * 512 + lbase;
        uint4 wa = *reinterpret_cast<const uint4*>(&wlds[base0]);
        uint4 wb = *reinterpret_cast<const uint4*>(&wlds[base0 + 256]);

        for (int d = n0; d < n1; ++d) {
            const int end_d = off[d + 1];
            float a0 = 0.f, a1 = 0.f;

            while (j < end_d) {
                int2 m3 = emeta[j + 3];
                const float4* hr2 = reinterpret_cast<const float4*>(
                    h + (size_t)((uint32_t)m2.x & 0xFFFFFu) * IN_F + b * 8);
                float4 h2A = hr2[0], h2B = hr2[1];
                uint32_t bn = ((uint32_t)m1.x >> 20) * 512 + lbase;
                uint4 wna = *reinterpret_cast<const uint4*>(&wlds[bn]);
                uint4 wnb = *reinterpret_cast<const uint4*>(&wlds[bn + 256]);

                uint32_t h01 = __builtin_bit_cast(uint32_t, __builtin_amdgcn_cvt_pkrtz(h0A.x, h0A.y));
                uint32_t h23 = __builtin_bit_cast(uint32_t, __builtin_amdgcn_cvt_pkrtz(h0A.z, h0A.w));
                uint32_t h45 = __builtin_bit_cast(uint32_t, __builtin_amdgcn_cvt_pkrtz(h0B.x, h0B.y));
                uint32_t h67 = __builtin_bit_cast(uint32_t, __builtin_amdgcn_cvt_pkrtz(h0B.z, h0B.w));

                float s0 = dot2f(h01, wa.x, 0.f);
                s0 = dot2f(h23, wa.y, s0);
                s0 = dot2f(h45, wa.z, s0);
                s0 = dot2f(h67, wa.w, s0);
                float s1 = dot2f(h01, wb.x, 0.f);
                s1 = dot2f(h23, wb.y, s1);
                s1 = dot2f(h45, wb.z, s1);
                s1 = dot2f(h67, wb.w, s1);

                const float nm = __int_as_float(m0.y);
                a0 = fmaf(s0, nm, a0);
                a1 = fmaf(s1, nm, a1);

                m0 = m1; m1 = m2; m2 = m3;
                h0A = h1A; h0B = h1B; h1A = h2A; h1B = h2B;
                wa = wna; wb = wnb;
                ++j;
            }

            float2* op = reinterpret_cast<float2*>(out + (size_t)d * OUT_F + b * 8 + 2 * q);
            float2 bse = *op;
            float2 res;
            res.x = fmaxf(bse.x + a0, 0.f);
            res.y = fmaxf(bse.y + a1, 0.f);
            *op = res;
        }
    }
}

extern "C" void kernel_launch(void* const* d_in, const int* in_sizes, int n_in,
                              void* d_out, int out_size, void* d_ws, size_t ws_size,
                              hipStream_t stream)
{
    const float* h      = (const float*)d_in[0];
    const float* norm   = (const float*)d_in[1];
    const float* weight = (const float*)d_in[2];
    const float* loop_w = (const float*)d_in[3];
    const float* bias   = (const float*)d_in[4];
    const int*   src    = (const int*)d_in[5];
    const int*   dst    = (const int*)d_in[6];
    const int*   rel    = (const int*)d_in[7];
    float* out = (float*)d_out;

    // ws layout: cnt[N], off[N+1], cur[N], part[512], wstart[N_WAVES+1],
    // wsw[64*512 u32], emeta[E+3] int2, h16[N*IN_F] fp16  -> ~35 MB
    char* wsb = (char*)d_ws;
    char* ws0 = wsb;
    int*  cnt    = (int*)wsb;  wsb += sizeof(int) * N_NODES;
    int*  off    = (int*)wsb;  wsb += sizeof(int) * (N_NODES + 1);
    int*  cur    = (int*)wsb;  wsb += sizeof(int) * N_NODES;
    int*  part   = (int*)wsb;  wsb += sizeof(int) * 512;
    int*  wstart = (int*)wsb;  wsb += sizeof(int) * (N_WAVES + 1);
    wsb = (char*)(((uintptr_t)wsb + 15) & ~(uintptr_t)15);
    uint32_t* wsw = (uint32_t*)wsb; wsb += sizeof(uint32_t) * NUM_RELS * 512;
    int2* emeta = (int2*)wsb;  wsb += sizeof(int2) * (N_EDGES + 3);
    wsb = (char*)(((uintptr_t)wsb + 15) & ~(uintptr_t)15);
    uint4* h16_4 = (uint4*)wsb; wsb += (size_t)N_NODES * IN_F * 2;

    const int use_h16 = (size_t)(wsb - ws0) <= ws_size;   // host-constant

    hipMemsetAsync(cnt, 0, sizeof(int) * N_NODES, stream);

    // CSR chain (independent of gemm/h16)
    const int hw_grid = (NUM_RELS * 512 + N_EDGES + 255) / 256;
    hist_wsw<<<hw_grid, 256, 0, stream>>>(weight, wsw, dst, cnt, N_EDGES);
    block_sums<<<NB_SCAN, 256, 0, stream>>>(cnt, part, N_NODES);
    write_off2<<<NB_SCAN, 256, 0, stream>>>(cnt, part, off, cur, N_NODES, N_EDGES);
    const int fp_grid = (N_EDGES + N_WAVES + 4 + 255) / 256;
    fill_and_part<<<fp_grid, 256, 0, stream>>>(src, dst, rel, norm, cur, emeta,
                                               off, wstart, N_EDGES);

    // self-loop GEMM + h16 side-product (h rows L2-hot per tile)
    gemm_h16<<<GEMM_TILES, 256, 0, stream>>>(h, loop_w, bias, out, h16_4, use_h16);

    if (use_h16) {
        gather_nodes10<<<GATHER_B, 1024, 0, stream>>>(h16_4, wsw, off, emeta, wstart, out);
    } else {
        gather_nodes6<<<GATHER_B, 1024, 0, stream>>>(h, wsw, off, emeta, wstart, out);
    }
}